// Round 3
// baseline (80.341 us; speedup 1.0000x reference)
//
#include <hip/hip_runtime.h>
#include <math.h>

#define BATCH 16384
#define NW 10
#define NENC 4
#define DEPTH 2

// ============================================================================
// z_w(x) = psi(x)^H (U^H D_w U) psi(x); encoded psi has support on 16 basis
// states a<<6 with psi_a = m_a (-i)^popc(a), m_a = prod of cos/sin halves.
//   C_w[a][b] = Re( i^(popc(a)-popc(b)) * sum_i sign_w(i) conj(u_a[i]) u_b[i] )
// Per-qubit double-angle: {c^2, cs, s^2} -> basis {1, cos x_q, sin x_q}:
//   z_w = sum_{t in 3^4} K_w[t] * prod_q basis_{t_q}(x_q)
//   K_w[t] = (1/16) * sum over 16 signed C entries  (k2b gather).
// k1: 16 waves propagate basis columns u_a.
// k2: 256 waves compute C (one wave per (a,b)).
// k2b: 1 block transforms C (256x10) -> K (81x10).
// k3: one thread per batch element: 81 products x 10 FMAs from LDS.
// ============================================================================

// ---- kernel 1: basis-column propagation --------------------------------
__global__ __launch_bounds__(256) void k1_basis(const float* __restrict__ theta,
                                                float2* __restrict__ u)
{
    const int lane = threadIdx.x & 63;
    const int a = (blockIdx.x * blockDim.x + threadIdx.x) >> 6;  // 0..15

    float re[16], im[16];
#pragma unroll
    for (int r = 0; r < 16; ++r) { re[r] = 0.0f; im[r] = 0.0f; }
    if (lane == 0) re[a] = 1.0f;     // |a<<6>

    float ct[NW], st_[NW];
#pragma unroll
    for (int w = 0; w < NW; ++w) {
        const float h = 0.5f * theta[w];
        ct[w] = __cosf(h); st_[w] = __sinf(h);
    }

#pragma unroll 1
    for (int d = 0; d < DEPTH; ++d) {
#pragma unroll
        for (int w = 0; w < 4; ++w) {            // RX on register wires
            const float c = ct[w], s = st_[w];
            const int m = 8 >> w;
#pragma unroll
            for (int r = 0; r < 16; ++r) {
                if (!(r & m)) {
                    const int r1 = r | m;
                    const float a0r = re[r],  a0i = im[r];
                    const float a1r = re[r1], a1i = im[r1];
                    re[r]  = c * a0r + s * a1i;
                    im[r]  = c * a0i - s * a1r;
                    re[r1] = c * a1r + s * a0i;
                    im[r1] = c * a1i - s * a0r;
                }
            }
        }
#pragma unroll
        for (int w = 4; w < 10; ++w) {           // RX on lane wires
            const float c = ct[w], s = st_[w];
            const int lm = 32 >> (w - 4);
#pragma unroll
            for (int r = 0; r < 16; ++r) {
                const float pr = __shfl_xor(re[r], lm, 64);
                const float pi = __shfl_xor(im[r], lm, 64);
                re[r] = c * re[r] + s * pi;
                im[r] = c * im[r] - s * pr;
            }
        }
        // ring CNOTs (0,1)(1,2)(2,3): register swaps
#pragma unroll
        for (int w = 0; w < 3; ++w) {
            const int cm = 8 >> w, tm = 8 >> (w + 1);
#pragma unroll
            for (int r = 0; r < 16; ++r) {
                if ((r & cm) && !(r & tm)) {
                    const int r2 = r | tm;
                    float t;
                    t = re[r]; re[r] = re[r2]; re[r2] = t;
                    t = im[r]; im[r] = im[r2]; im[r2] = t;
                }
            }
        }
        // (3,4): odd registers swap lanes across bit5
#pragma unroll
        for (int r = 0; r < 16; ++r) {
            if (r & 1) {
                re[r] = __shfl_xor(re[r], 32, 64);
                im[r] = __shfl_xor(im[r], 32, 64);
            }
        }
        // (4,5)..(8,9): lane-bit CNOTs
#pragma unroll
        for (int w = 4; w < 9; ++w) {
            const int cm = 32 >> (w - 4), tm = 32 >> (w - 3);
            const bool ctl = (lane & cm) != 0;
#pragma unroll
            for (int r = 0; r < 16; ++r) {
                const float pr = __shfl_xor(re[r], tm, 64);
                const float pi = __shfl_xor(im[r], tm, 64);
                re[r] = ctl ? pr : re[r];
                im[r] = ctl ? pi : im[r];
            }
        }
        // (9,0): lane-bit0 controlled register-bit3 swap
        {
            const bool ctl = (lane & 1) != 0;
#pragma unroll
            for (int r = 0; r < 8; ++r) {
                const float t0r = re[r], t1r = re[r + 8];
                const float t0i = im[r], t1i = im[r + 8];
                re[r]     = ctl ? t1r : t0r;
                re[r + 8] = ctl ? t0r : t1r;
                im[r]     = ctl ? t1i : t0i;
                im[r + 8] = ctl ? t0i : t1i;
            }
        }
    }

#pragma unroll
    for (int r = 0; r < 16; ++r)
        u[a * 1024 + (r << 6) + lane] = make_float2(re[r], im[r]);
}

// ---- kernel 2: Gram matrices with Z signs, phase-folded ----------------
__global__ __launch_bounds__(256) void k2_gram(const float2* __restrict__ u,
                                               float* __restrict__ C)
{
    const int lane = threadIdx.x & 63;
    const int q = (blockIdx.x * blockDim.x + threadIdx.x) >> 6;  // 0..255
    const int a = q >> 4, b = q & 15;

    float Sr[NW], Si[NW];
#pragma unroll
    for (int w = 0; w < NW; ++w) { Sr[w] = 0.0f; Si[w] = 0.0f; }

#pragma unroll
    for (int t = 0; t < 16; ++t) {
        const int i = t * 64 + lane;
        const float2 ua = u[a * 1024 + i];
        const float2 ub = u[b * 1024 + i];
        const float vr = ua.x * ub.x + ua.y * ub.y;   // Re(conj(ua)*ub)
        const float vi = ua.x * ub.y - ua.y * ub.x;   // Im(conj(ua)*ub)
#pragma unroll
        for (int w = 0; w < NW; ++w) {
            const int mask = 1 << (9 - w);
            const float sv = (i & mask) ? -1.0f : 1.0f;
            Sr[w] = fmaf(sv, vr, Sr[w]);
            Si[w] = fmaf(sv, vi, Si[w]);
        }
    }
#pragma unroll
    for (int w = 0; w < NW; ++w) {
        float r = Sr[w], ii = Si[w];
#pragma unroll
        for (int ofs = 32; ofs >= 1; ofs >>= 1) {
            r  += __shfl_xor(r,  ofs, 64);
            ii += __shfl_xor(ii, ofs, 64);
        }
        Sr[w] = r; Si[w] = ii;
    }

    if (lane == 0) {
        const int p = (__popc(a) - __popc(b)) & 3;
#pragma unroll
        for (int w = 0; w < NW; ++w) {
            const float sr = Sr[w], si = Si[w];
            const float c = (p == 0) ? sr : (p == 1) ? -si : (p == 2) ? -sr : si;
            C[q * 12 + w] = c;
        }
    }
}

// ---- kernel 2b: C (pairs) -> K (trig basis), 81x10 ---------------------
// Per qubit q, (a_q,b_q) -> basis {1,cos,sin} weights:
//   (0,0):(1/2,1/2,0)  (0,1)/(1,0):(0,0,1/2)  (1,1):(1/2,-1/2,0)
// So K_w[t] = (1/16) * sum over 16 enumerations e of sgn * C_w[a(e),b(e)].
__global__ __launch_bounds__(832) void k2b_xform(const float* __restrict__ C,
                                                 float* __restrict__ K)
{
    const int tid = threadIdx.x;
    if (tid >= 810) return;
    const int t = tid / 10, w = tid - 10 * t;
    int d0 = t / 27, r0 = t - d0 * 27;
    int d1 = r0 / 9, r1 = r0 - d1 * 9;
    int d2 = r1 / 3, d3 = r1 - d2 * 3;
    const int d[4] = { d0, d1, d2, d3 };

    float s = 0.0f;
#pragma unroll
    for (int e = 0; e < 16; ++e) {
        int a = 0, b = 0; float sg = 1.0f;
#pragma unroll
        for (int q = 0; q < 4; ++q) {
            const int eq = (e >> (3 - q)) & 1;
            int aq, bq;
            if (d[q] == 2) { aq = eq; bq = 1 - eq; }
            else {
                aq = eq; bq = eq;
                if (d[q] == 1 && eq) sg = -sg;
            }
            a |= aq << (3 - q);
            b |= bq << (3 - q);
        }
        s += sg * C[(a * 16 + b) * 12 + w];
    }
    K[t * 12 + w] = s * 0.0625f;
}

// ---- kernel 3: per-batch trig-basis evaluation -------------------------
__global__ __launch_bounds__(128) void k3_eval(const float* __restrict__ x,
                                               const float* __restrict__ K,
                                               float* __restrict__ out)
{
    __shared__ float lK[81 * 12];
    for (int i = threadIdx.x; i < 81 * 12; i += 128) lK[i] = K[i];
    __syncthreads();

    const int bidx = blockIdx.x * 128 + threadIdx.x;
    const float4 xv = ((const float4*)x)[bidx];

    float s0, c0, s1, c1, s2, c2, s3, c3;
    __sincosf(xv.x, &s0, &c0);
    __sincosf(xv.y, &s1, &c1);
    __sincosf(xv.z, &s2, &c2);
    __sincosf(xv.w, &s3, &c3);

    const float b0[3] = { 1.0f, c0, s0 };
    const float b1[3] = { 1.0f, c1, s1 };
    const float b2[3] = { 1.0f, c2, s2 };
    const float b3[3] = { 1.0f, c3, s3 };
    float B01[9], B23[9];
#pragma unroll
    for (int i = 0; i < 3; ++i)
#pragma unroll
        for (int j = 0; j < 3; ++j) {
            B01[i * 3 + j] = b0[i] * b1[j];
            B23[i * 3 + j] = b2[i] * b3[j];
        }

    float z[NW];
#pragma unroll
    for (int w = 0; w < NW; ++w) z[w] = 0.0f;

#pragma unroll
    for (int t01 = 0; t01 < 9; ++t01) {
#pragma unroll
        for (int t23 = 0; t23 < 9; ++t23) {
            const float P = B01[t01] * B23[t23];
            const float* base = &lK[(t01 * 9 + t23) * 12];
            const float4 q0 = *(const float4*)(base + 0);
            const float4 q1 = *(const float4*)(base + 4);
            const float4 q2 = *(const float4*)(base + 8);
            z[0] = fmaf(P, q0.x, z[0]);
            z[1] = fmaf(P, q0.y, z[1]);
            z[2] = fmaf(P, q0.z, z[2]);
            z[3] = fmaf(P, q0.w, z[3]);
            z[4] = fmaf(P, q1.x, z[4]);
            z[5] = fmaf(P, q1.y, z[5]);
            z[6] = fmaf(P, q1.z, z[6]);
            z[7] = fmaf(P, q1.w, z[7]);
            z[8] = fmaf(P, q2.x, z[8]);
            z[9] = fmaf(P, q2.y, z[9]);
        }
    }

    // out row is 40 B -> 8 B aligned; 5x float2 stores
    float2* po = (float2*)(out + bidx * NW);
    po[0] = make_float2(z[0], z[1]);
    po[1] = make_float2(z[2], z[3]);
    po[2] = make_float2(z[4], z[5]);
    po[3] = make_float2(z[6], z[7]);
    po[4] = make_float2(z[8], z[9]);
}

extern "C" void kernel_launch(void* const* d_in, const int* in_sizes, int n_in,
                              void* d_out, int out_size, void* d_ws, size_t ws_size,
                              hipStream_t stream) {
    const float* x     = (const float*)d_in[0];
    const float* theta = (const float*)d_in[1];
    float* out = (float*)d_out;

    float2* u = (float2*)d_ws;                                      // 131072 B
    float*  C = (float*)((char*)d_ws + 16 * 1024 * sizeof(float2)); // 12288 B
    float*  K = C + 256 * 12;                                       // 3888 B

    hipLaunchKernelGGL(k1_basis,  dim3(4),   dim3(256), 0, stream, theta, u);
    hipLaunchKernelGGL(k2_gram,   dim3(64),  dim3(256), 0, stream, u, C);
    hipLaunchKernelGGL(k2b_xform, dim3(1),   dim3(832), 0, stream, C, K);
    hipLaunchKernelGGL(k3_eval,   dim3(BATCH / 128), dim3(128), 0, stream, x, K, out);
}